// Round 1
// baseline (289858.667 us; speedup 1.0000x reference)
//
#include <hip/hip_runtime.h>
#include <stdint.h>

#define Ic 128   // input size
#define Hc 256   // hidden size
#define G4 1024  // 4*H
#define NT 1024  // threads per block

using half2v = __attribute__((ext_vector_type(2))) _Float16;

// pack two fp32 -> fp16x2, round-to-nearest-even (accuracy)
__device__ __forceinline__ uint32_t pk_rne(float a, float b) {
    _Float16 lo = (_Float16)a, hi = (_Float16)b;
    uint16_t ul = __builtin_bit_cast(uint16_t, lo);
    uint16_t uh = __builtin_bit_cast(uint16_t, hi);
    return (uint32_t)ul | ((uint32_t)uh << 16);
}

__device__ __forceinline__ float dot2acc(uint32_t a, uint32_t b, float c) {
#if __has_builtin(__builtin_amdgcn_fdot2)
    return __builtin_amdgcn_fdot2(__builtin_bit_cast(half2v, a),
                                  __builtin_bit_cast(half2v, b), c, false);
#else
    half2v av = __builtin_bit_cast(half2v, a);
    half2v bv = __builtin_bit_cast(half2v, b);
    return c + (float)av[0] * (float)bv[0] + (float)av[1] * (float)bv[1];
#endif
}

__device__ __forceinline__ uint32_t rl(uint32_t v, int k) {
    return (uint32_t)__builtin_amdgcn_readlane((int)v, k);
}

__device__ __forceinline__ float sigm(float x) {
    return __builtin_amdgcn_rcpf(1.f + __expf(-x));
}
__device__ __forceinline__ float tanh_f(float x) {
    float e = __expf(-2.f * __builtin_fabsf(x));
    float t = (1.f - e) * __builtin_amdgcn_rcpf(1.f + e);
    return __builtin_copysignf(t, x);
}

// ---------------- Encoder: 128 blocks = 64 fwd + 64 bwd, one block per (dir,batch) ----------------
__global__ __launch_bounds__(NT, 1) void enc_kernel(
    const float* __restrict__ x,
    const float* __restrict__ WihF, const float* __restrict__ WhhF,
    const float* __restrict__ bihF, const float* __restrict__ bhhF,
    const float* __restrict__ WihB, const float* __restrict__ WhhB,
    const float* __restrict__ bihB, const float* __restrict__ bhhB,
    float* __restrict__ hF, float* __restrict__ hB, int T)
{
    const int t    = threadIdx.x;
    const int lane = t & 63;
    const int rev  = blockIdx.x >> 6;
    const int b    = blockIdx.x & 63;

    const float* Wih = rev ? WihB : WihF;
    const float* Whh = rev ? WhhB : WhhF;
    const float* bih = rev ? bihB : bihF;
    const float* bhh = rev ? bhhB : bhhF;

    __shared__ uint32_t s_hpk[Hc / 2];  // h packed fp16x2
    __shared__ uint32_t s_xpk[Ic / 2];  // x_t packed fp16x2
    __shared__ float    s_g[G4];        // gate pre-activations

    // per-thread weights (gate row t), packed fp16x2 in registers
    uint32_t whh_pk[Hc / 2];
    uint32_t wih_pk[Ic / 2];
    {
        const float* wp = Whh + (size_t)t * Hc;
#pragma unroll
        for (int k = 0; k < Hc / 2; k++) whh_pk[k] = pk_rne(wp[2 * k], wp[2 * k + 1]);
        const float* ip = Wih + (size_t)t * Ic;
#pragma unroll
        for (int k = 0; k < Ic / 2; k++) wih_pk[k] = pk_rne(ip[2 * k], ip[2 * k + 1]);
    }
    const float bias = bih[t] + bhh[t];

    float c0 = 0.f, c1 = 0.f;  // cell state (threads 0..127 own hidden pair 2t,2t+1)

    if (t < Hc / 2) s_hpk[t] = 0u;  // h0 = 0
    if (t >= 128 && t < 192) {      // stage x for step 0
        int m = t - 128;
        int ts0 = rev ? (T - 1) : 0;
        const float* xp = x + ((size_t)b * T + ts0) * Ic + 2 * m;
        s_xpk[m] = pk_rne(xp[0], xp[1]);
    }
    __syncthreads();

    for (int s = 0; s < T; s++) {
        uint32_t vh0 = s_hpk[lane];
        uint32_t vh1 = s_hpk[64 + lane];
        uint32_t vx  = s_xpk[lane];

        float a0 = bias, a1 = 0.f;
#pragma unroll
        for (int k = 0; k < 64; k++) {
            uint32_t hp = rl(vh0, k);
            if (k & 1) a1 = dot2acc(hp, whh_pk[k], a1);
            else       a0 = dot2acc(hp, whh_pk[k], a0);
        }
#pragma unroll
        for (int k = 0; k < 64; k++) {
            uint32_t hp = rl(vh1, k);
            if (k & 1) a1 = dot2acc(hp, whh_pk[64 + k], a1);
            else       a0 = dot2acc(hp, whh_pk[64 + k], a0);
        }
#pragma unroll
        for (int k = 0; k < 64; k++) {
            uint32_t xp = rl(vx, k);
            if (k & 1) a1 = dot2acc(xp, wih_pk[k], a1);
            else       a0 = dot2acc(xp, wih_pk[k], a0);
        }
        s_g[t] = a0 + a1;
        __syncthreads();

        if (t < 128) {  // activation: thread owns hidden units 2t, 2t+1
            float2 gi = *(const float2*)&s_g[2 * t];
            float2 gf = *(const float2*)&s_g[Hc + 2 * t];
            float2 gg = *(const float2*)&s_g[2 * Hc + 2 * t];
            float2 go = *(const float2*)&s_g[3 * Hc + 2 * t];
            c0 = sigm(gf.x) * c0 + sigm(gi.x) * tanh_f(gg.x);
            c1 = sigm(gf.y) * c1 + sigm(gi.y) * tanh_f(gg.y);
            float h0 = sigm(go.x) * tanh_f(c0);
            float h1 = sigm(go.y) * tanh_f(c1);
            s_hpk[t] = pk_rne(h0, h1);
            if (s == T - 1) {
                float* ho = (rev ? hB : hF) + (size_t)b * Hc + 2 * t;
                ho[0] = h0; ho[1] = h1;
            }
        } else if (t < 192) {  // stage x for step s+1
            int sn = s + 1;
            if (sn < T) {
                int m = t - 128;
                int ts = rev ? (T - 1 - sn) : sn;
                const float* xp = x + ((size_t)b * T + ts) * Ic + 2 * m;
                s_xpk[m] = pk_rne(xp[0], xp[1]);
            }
        }
        __syncthreads();
    }
}

// ---------------- Latent bottleneck: hidden[b] = l2h(lat(concat(hF,hB))) ----------------
__global__ void lat_kernel(const float* __restrict__ hF, const float* __restrict__ hB,
                           const float* __restrict__ latW, const float* __restrict__ latb,
                           const float* __restrict__ l2hW, const float* __restrict__ l2hb,
                           float* __restrict__ hidden)
{
    int b = blockIdx.x, t = threadIdx.x;  // 256 threads
    __shared__ float s_hn[512];
    __shared__ float s_lat[64];
    s_hn[t]       = hF[(size_t)b * Hc + t];
    s_hn[256 + t] = hB[(size_t)b * Hc + t];
    __syncthreads();
    if (t < 64) {
        float a = latb[t];
        const float* wp = latW + (size_t)t * 512;
        for (int k = 0; k < 512; k++) a += wp[k] * s_hn[k];
        s_lat[t] = a;
    }
    __syncthreads();
    float a = l2hb[t];
    const float* wp = l2hW + (size_t)t * 64;
#pragma unroll
    for (int k = 0; k < 64; k++) a += wp[k] * s_lat[k];
    hidden[(size_t)b * Hc + t] = a;
}

// ---------------- Decoder: 64 blocks, fused output projection ----------------
__global__ __launch_bounds__(NT, 1) void dec_kernel(
    const float* __restrict__ x,
    const float* __restrict__ Wih, const float* __restrict__ Whh,
    const float* __restrict__ bih, const float* __restrict__ bhh,
    const float* __restrict__ outW, const float* __restrict__ outb,
    const float* __restrict__ hidden, float* __restrict__ out, int T)
{
    const int t    = threadIdx.x;
    const int lane = t & 63;
    const int b    = blockIdx.x;
    const int Ts   = T - 1;  // 4095 decoder steps

    __shared__ uint32_t s_hpk[Hc / 2];
    __shared__ uint32_t s_xpk[Ic / 2];
    __shared__ float    s_g[G4];
    __shared__ float    s_ep[G4];  // epilogue partials

    uint32_t whh_pk[Hc / 2];
    uint32_t wih_pk[Ic / 2];
    uint32_t outw_pk[16];  // out-proj slice: row (t&127), h-chunk (t>>7)*32..+32
    {
        const float* wp = Whh + (size_t)t * Hc;
#pragma unroll
        for (int k = 0; k < Hc / 2; k++) whh_pk[k] = pk_rne(wp[2 * k], wp[2 * k + 1]);
        const float* ip = Wih + (size_t)t * Ic;
#pragma unroll
        for (int k = 0; k < Ic / 2; k++) wih_pk[k] = pk_rne(ip[2 * k], ip[2 * k + 1]);
    }
    const int er = t & 127;  // out row
    const int eq = t >> 7;   // chunk (wave-uniform)
    {
        const float* op = outW + (size_t)er * Hc + eq * 32;
#pragma unroll
        for (int j = 0; j < 16; j++) outw_pk[j] = pk_rne(op[2 * j], op[2 * j + 1]);
    }
    const float bias = bih[t] + bhh[t];

    float c0 = 0.f, c1 = 0.f;
    if (t < 128) {  // h0 = hidden[b]
        const float* hp = hidden + (size_t)b * Hc + 2 * t;
        s_hpk[t] = pk_rne(hp[0], hp[1]);
    }
    if (t >= 128 && t < 192) {  // stage x for step 0
        int m = t - 128;
        const float* xp = x + ((size_t)b * T + 0) * Ic + 2 * m;
        s_xpk[m] = pk_rne(xp[0], xp[1]);
    }
    __syncthreads();

    for (int s = 0; s < Ts; s++) {
        uint32_t vh0 = s_hpk[lane];
        uint32_t vh1 = s_hpk[64 + lane];
        uint32_t vx  = s_xpk[lane];

        float a0 = bias, a1 = 0.f;
#pragma unroll
        for (int k = 0; k < 64; k++) {
            uint32_t hp = rl(vh0, k);
            if (k & 1) a1 = dot2acc(hp, whh_pk[k], a1);
            else       a0 = dot2acc(hp, whh_pk[k], a0);
        }
#pragma unroll
        for (int k = 0; k < 64; k++) {
            uint32_t hp = rl(vh1, k);
            if (k & 1) a1 = dot2acc(hp, whh_pk[64 + k], a1);
            else       a0 = dot2acc(hp, whh_pk[64 + k], a0);
        }
#pragma unroll
        for (int k = 0; k < 64; k++) {
            uint32_t xp = rl(vx, k);
            if (k & 1) a1 = dot2acc(xp, wih_pk[k], a1);
            else       a0 = dot2acc(xp, wih_pk[k], a0);
        }
        s_g[t] = a0 + a1;

        if (s > 0) {  // output-projection partial for step s-1 (s_hpk holds h_{s-1})
            float ep = 0.f;
#pragma unroll
            for (int j = 0; j < 16; j++) {
                int p = eq * 16 + j;
                uint32_t hp = rl(eq < 4 ? vh0 : vh1, p & 63);
                ep = dot2acc(hp, outw_pk[j], ep);
            }
            s_ep[t] = ep;
        }
        __syncthreads();

        if (t < 128) {  // activation
            float2 gi = *(const float2*)&s_g[2 * t];
            float2 gf = *(const float2*)&s_g[Hc + 2 * t];
            float2 gg = *(const float2*)&s_g[2 * Hc + 2 * t];
            float2 go = *(const float2*)&s_g[3 * Hc + 2 * t];
            c0 = sigm(gf.x) * c0 + sigm(gi.x) * tanh_f(gg.x);
            c1 = sigm(gf.y) * c1 + sigm(gi.y) * tanh_f(gg.y);
            float h0 = sigm(go.x) * tanh_f(c0);
            float h1 = sigm(go.y) * tanh_f(c1);
            s_hpk[t] = pk_rne(h0, h1);
        } else if (t < 192) {  // stage x for step s+1
            int sn = s + 1;
            if (sn < Ts) {
                int m = t - 128;
                const float* xp = x + ((size_t)b * T + sn) * Ic + 2 * m;
                s_xpk[m] = pk_rne(xp[0], xp[1]);
            }
        } else if (t < 320 && s > 0) {  // reduce + store decoded[b, s-1]
            int r = t - 192;
            float y = outb[r];
#pragma unroll
            for (int q = 0; q < 8; q++) y += s_ep[r + 128 * q];
            out[((size_t)b * Ts + (s - 1)) * Ic + r] = y;
        }
        __syncthreads();
    }

    // tail: output projection for the last step (h_{Ts-1} is in s_hpk)
    {
        uint32_t vh0 = s_hpk[lane];
        uint32_t vh1 = s_hpk[64 + lane];
        float ep = 0.f;
#pragma unroll
        for (int j = 0; j < 16; j++) {
            int p = eq * 16 + j;
            uint32_t hp = rl(eq < 4 ? vh0 : vh1, p & 63);
            ep = dot2acc(hp, outw_pk[j], ep);
        }
        s_ep[t] = ep;
        __syncthreads();
        if (t >= 192 && t < 320) {
            int r = t - 192;
            float y = outb[r];
#pragma unroll
            for (int q = 0; q < 8; q++) y += s_ep[r + 128 * q];
            out[((size_t)b * Ts + (Ts - 1)) * Ic + r] = y;
        }
    }
}

extern "C" void kernel_launch(void* const* d_in, const int* in_sizes, int n_in,
                              void* d_out, int out_size, void* d_ws, size_t ws_size,
                              hipStream_t stream)
{
    const float* x    = (const float*)d_in[0];
    const float* WihF = (const float*)d_in[1];
    const float* WhhF = (const float*)d_in[2];
    const float* bihF = (const float*)d_in[3];
    const float* bhhF = (const float*)d_in[4];
    const float* WihB = (const float*)d_in[5];
    const float* WhhB = (const float*)d_in[6];
    const float* bihB = (const float*)d_in[7];
    const float* bhhB = (const float*)d_in[8];
    const float* latW = (const float*)d_in[9];
    const float* latb = (const float*)d_in[10];
    const float* l2hW = (const float*)d_in[11];
    const float* l2hb = (const float*)d_in[12];
    const float* dWih = (const float*)d_in[13];
    const float* dWhh = (const float*)d_in[14];
    const float* dbih = (const float*)d_in[15];
    const float* dbhh = (const float*)d_in[16];
    const float* outW = (const float*)d_in[17];
    const float* outb = (const float*)d_in[18];

    const int T = in_sizes[0] / (64 * Ic);  // 4096

    float* ws     = (float*)d_ws;
    float* hF     = ws;                 // [64,256]
    float* hB     = ws + 64 * Hc;       // [64,256]
    float* hidden = ws + 2 * 64 * Hc;   // [64,256]

    enc_kernel<<<128, NT, 0, stream>>>(x, WihF, WhhF, bihF, bhhF,
                                       WihB, WhhB, bihB, bhhB, hF, hB, T);
    lat_kernel<<<64, 256, 0, stream>>>(hF, hB, latW, latb, l2hW, l2hb, hidden);
    dec_kernel<<<64, NT, 0, stream>>>(x, dWih, dWhh, dbih, dbhh,
                                      outW, outb, hidden, (float*)d_out, T);
}

// Round 3
// 244020.166 us; speedup vs baseline: 1.1878x; 1.1878x over previous
//
#include <hip/hip_runtime.h>
#include <stdint.h>

#define Ic 128   // input size
#define Hc 256   // hidden size
#define ZU 192   // (H+I)/2 packed u32 width of z = [h | x]
#define NT 1024

using half2v = __attribute__((ext_vector_type(2))) _Float16;

__device__ __forceinline__ uint32_t pk_rne(float a, float b) {
    _Float16 lo = (_Float16)a, hi = (_Float16)b;
    return (uint32_t)__builtin_bit_cast(uint16_t, lo) |
           ((uint32_t)__builtin_bit_cast(uint16_t, hi) << 16);
}
__device__ __forceinline__ float dot2acc(uint32_t a, uint32_t b, float c) {
    return __builtin_amdgcn_fdot2(__builtin_bit_cast(half2v, a),
                                  __builtin_bit_cast(half2v, b), c, false);
}
__device__ __forceinline__ uint32_t rl(uint32_t v, int k) {
    return (uint32_t)__builtin_amdgcn_readlane((int)v, k);
}
__device__ __forceinline__ float sigm(float x) {
    return __builtin_amdgcn_rcpf(1.f + __expf(-x));
}
__device__ __forceinline__ float tanh_f(float x) {
    float e = __expf(-2.f * __builtin_fabsf(x));
    float t = (1.f - e) * __builtin_amdgcn_rcpf(1.f + e);
    return __builtin_copysignf(t, x);
}

// ============ Encoder: 256 blocks = (64 batch × 2 dir) pairs × 2 halves ============
// Pair pb = blockIdx>>1 (dir = pb>>6, b = pb&63); half = blockIdx&1 owns gate rows
// [half*512, half*512+512). Thread t: row = half*512 + (t&511), K-slice q = t>>9
// covering packed z-cols [q*96, q*96+96) of z = [h(256) | x(128)].
// Halves exchange fp32 gates each step (parity double-buffered) and redundantly
// compute bit-identical c,h.
__global__ __launch_bounds__(NT, 1) void enc_kernel(
    const float* __restrict__ x,
    const float* __restrict__ WihF, const float* __restrict__ WhhF,
    const float* __restrict__ bihF, const float* __restrict__ bhhF,
    const float* __restrict__ WihB, const float* __restrict__ WhhB,
    const float* __restrict__ bihB, const float* __restrict__ bhhB,
    float* __restrict__ hF, float* __restrict__ hB,
    uint32_t* __restrict__ xch,    // [128 pairs][2 halves][2 parity][512]
    uint32_t* __restrict__ flags,  // [128 pairs][2]
    int T)
{
    const int t    = threadIdx.x;
    const int lane = t & 63;
    const int half = blockIdx.x & 1;
    const int pb   = blockIdx.x >> 1;
    const int rev  = pb >> 6;
    const int b    = pb & 63;
    const int rloc = t & 511;
    const int q    = t >> 9;          // K-slice 0/1
    const int r    = half * 512 + rloc;

    const float* Wih = rev ? WihB : WihF;
    const float* Whh = rev ? WhhB : WhhF;
    const float* bih = rev ? bihB : bihF;
    const float* bhh = rev ? bhhB : bhhF;

    __shared__ uint32_t s_zpk[ZU];   // [0:128) h pairs fp16x2, [128:192) x pairs
    __shared__ float    s_part[NT];
    __shared__ float    s_g[1024];   // full fp32 gate vector (global row order)

    // per-thread weights: row r, packed z-col slice [q*96, q*96+96)
    uint32_t w_pk[96];
#pragma unroll
    for (int j = 0; j < 96; j++) {
        int m = q * 96 + j;
        float w0, w1;
        if (m < 128) { w0 = Whh[(size_t)r * Hc + 2 * m];       w1 = Whh[(size_t)r * Hc + 2 * m + 1]; }
        else         { w0 = Wih[(size_t)r * Ic + 2 * m - 256]; w1 = Wih[(size_t)r * Ic + 2 * m - 255]; }
        w_pk[j] = pk_rne(w0, w1);
    }
    const float bias = (q == 0) ? (bih[r] + bhh[r]) : 0.f;

    uint32_t* xch_self  = xch + ((size_t)(pb * 2 + half)) * 1024;      // ×2 parity ×512
    uint32_t* xch_peer  = xch + ((size_t)(pb * 2 + (half ^ 1))) * 1024;
    uint32_t* flag_self = flags + pb * 2 + half;
    uint32_t* flag_peer = flags + pb * 2 + (half ^ 1);

    if (t < 128) s_zpk[t] = 0u;  // h0 = 0
    if (t >= 128 && t < 192) {   // stage x for step 0
        int m = t - 128;
        int ts0 = rev ? (T - 1) : 0;
        const float* xp = x + ((size_t)b * T + ts0) * Ic + 2 * m;
        s_zpk[128 + m] = pk_rne(xp[0], xp[1]);
    }
    __syncthreads();

    float c0 = 0.f, c1 = 0.f;
    for (int s = 0; s < T; s++) {
        const int par = s & 1;
        uint32_t vz0 = s_zpk[q * 96 + lane];
        uint32_t vz1 = s_zpk[q * 96 + 64 + (lane & 31)];
        float a0 = bias, a1 = 0.f, a2 = 0.f, a3 = 0.f;
#pragma unroll
        for (int k = 0; k < 64; k += 4) {
            a0 = dot2acc(rl(vz0, k + 0), w_pk[k + 0], a0);
            a1 = dot2acc(rl(vz0, k + 1), w_pk[k + 1], a1);
            a2 = dot2acc(rl(vz0, k + 2), w_pk[k + 2], a2);
            a3 = dot2acc(rl(vz0, k + 3), w_pk[k + 3], a3);
        }
#pragma unroll
        for (int k = 0; k < 32; k += 4) {
            a0 = dot2acc(rl(vz1, k + 0), w_pk[64 + k + 0], a0);
            a1 = dot2acc(rl(vz1, k + 1), w_pk[64 + k + 1], a1);
            a2 = dot2acc(rl(vz1, k + 2), w_pk[64 + k + 2], a2);
            a3 = dot2acc(rl(vz1, k + 3), w_pk[64 + k + 3], a3);
        }
        s_part[t] = (a0 + a1) + (a2 + a3);
        __syncthreads();

        // reduce own-half gates (fp32), publish to peer (parity buffer)
        if (t < 512) {
            float g = s_part[t] + s_part[t + 512];
            s_g[half * 512 + t] = g;
            __hip_atomic_store(&xch_self[par * 512 + t],
                               __builtin_bit_cast(uint32_t, g),
                               __ATOMIC_RELAXED, __HIP_MEMORY_SCOPE_AGENT);
            __threadfence();
        }
        __syncthreads();
        if (t == 0)
            __hip_atomic_store(flag_self, (uint32_t)(s + 1), __ATOMIC_RELEASE, __HIP_MEMORY_SCOPE_AGENT);
        if (t == 64) {
            while (__hip_atomic_load(flag_peer, __ATOMIC_ACQUIRE, __HIP_MEMORY_SCOPE_AGENT) < (uint32_t)(s + 1))
                __builtin_amdgcn_s_sleep(1);
        }
        __syncthreads();
        if (t < 512) {
            uint32_t u = __hip_atomic_load(&xch_peer[par * 512 + t],
                                           __ATOMIC_RELAXED, __HIP_MEMORY_SCOPE_AGENT);
            s_g[(half ^ 1) * 512 + t] = __builtin_bit_cast(float, u);
        }
        __syncthreads();

        // identical redundant cell update on both halves (inputs bit-identical)
        if (t < 128) {
            float i0 = s_g[2 * t],       i1 = s_g[2 * t + 1];
            float f0 = s_g[256 + 2 * t], f1 = s_g[256 + 2 * t + 1];
            float g0 = s_g[512 + 2 * t], g1 = s_g[512 + 2 * t + 1];
            float o0 = s_g[768 + 2 * t], o1 = s_g[768 + 2 * t + 1];
            c0 = sigm(f0) * c0 + sigm(i0) * tanh_f(g0);
            c1 = sigm(f1) * c1 + sigm(i1) * tanh_f(g1);
            float h0 = sigm(o0) * tanh_f(c0);
            float h1 = sigm(o1) * tanh_f(c1);
            s_zpk[t] = pk_rne(h0, h1);
            if (s == T - 1 && half == 0) {
                float* ho = (rev ? hB : hF) + (size_t)b * Hc + 2 * t;
                ho[0] = h0; ho[1] = h1;
            }
        } else if (t < 192) {  // stage x for step s+1
            int sn = s + 1;
            if (sn < T) {
                int m = t - 128;
                int ts = rev ? (T - 1 - sn) : sn;
                const float* xp = x + ((size_t)b * T + ts) * Ic + 2 * m;
                s_zpk[128 + m] = pk_rne(xp[0], xp[1]);
            }
        }
        __syncthreads();
    }
}

// ============ Latent bottleneck ============
__global__ void lat_kernel(const float* __restrict__ hF, const float* __restrict__ hB,
                           const float* __restrict__ latW, const float* __restrict__ latb,
                           const float* __restrict__ l2hW, const float* __restrict__ l2hb,
                           float* __restrict__ hidden)
{
    int b = blockIdx.x, t = threadIdx.x;  // 256 threads
    __shared__ float s_hn[512];
    __shared__ float s_lat[64];
    s_hn[t]       = hF[(size_t)b * Hc + t];
    s_hn[256 + t] = hB[(size_t)b * Hc + t];
    __syncthreads();
    if (t < 64) {
        float a = latb[t];
        const float* wp = latW + (size_t)t * 512;
        for (int k = 0; k < 512; k++) a += wp[k] * s_hn[k];
        s_lat[t] = a;
    }
    __syncthreads();
    float a = l2hb[t];
    const float* wp = l2hW + (size_t)t * 64;
#pragma unroll
    for (int k = 0; k < 64; k++) a += wp[k] * s_lat[k];
    hidden[(size_t)b * Hc + t] = a;
}

// ============ Decoder: 256 blocks = 64 batches × 4 quarters ============
// Quarter q4 owns gate rows [q4*256, q4*256+256). Thread t: row = q4*256 + (t&255),
// K-slice ks = t>>8 covering packed z-cols [ks*48, ks*48+48).
// Quarters exchange fp32 gates (parity double-buffered), redundantly update c/h,
// and each computes 32 of the 128 fused output-projection rows.
__global__ __launch_bounds__(NT, 1) void dec_kernel(
    const float* __restrict__ x,
    const float* __restrict__ Wih, const float* __restrict__ Whh,
    const float* __restrict__ bih, const float* __restrict__ bhh,
    const float* __restrict__ outW, const float* __restrict__ outb,
    const float* __restrict__ hidden, float* __restrict__ out,
    uint32_t* __restrict__ xch,    // [64 batches][2 parity][1024]
    uint32_t* __restrict__ flags,  // [64][4]
    int T)
{
    const int t    = threadIdx.x;
    const int lane = t & 63;
    const int q4   = blockIdx.x & 3;
    const int b    = blockIdx.x >> 2;
    const int Ts   = T - 1;
    const int rloc = t & 255;
    const int ks   = t >> 8;           // K-slice 0..3
    const int r    = q4 * 256 + rloc;

    __shared__ uint32_t s_zpk[ZU];
    __shared__ float    s_part[NT];
    __shared__ float    s_g[1024];
    __shared__ float    s_op[512];

    uint32_t w_pk[48];
#pragma unroll
    for (int j = 0; j < 48; j++) {
        int m = ks * 48 + j;
        float w0, w1;
        if (m < 128) { w0 = Whh[(size_t)r * Hc + 2 * m];       w1 = Whh[(size_t)r * Hc + 2 * m + 1]; }
        else         { w0 = Wih[(size_t)r * Ic + 2 * m - 256]; w1 = Wih[(size_t)r * Ic + 2 * m - 255]; }
        w_pk[j] = pk_rne(w0, w1);
    }
    const float bias = (ks == 0) ? (bih[r] + bhh[r]) : 0.f;

    // fused projection weights: thread t<512 handles out row q4*32+(t>>4), h-chunk t&15
    const int orow  = q4 * 32 + ((t >> 4) & 31);
    const int chunk = t & 15;
    uint32_t outw_pk[8];
#pragma unroll
    for (int j = 0; j < 8; j++) {
        if (t < 512) {
            const float* op = outW + (size_t)orow * Hc + (chunk * 8 + j) * 2;
            outw_pk[j] = pk_rne(op[0], op[1]);
        } else outw_pk[j] = 0u;
    }

    uint32_t* xch_b  = xch + (size_t)b * 2048;   // 2 parity × 1024
    uint32_t* flag_b = flags + b * 4;

    if (t < 128) {  // h0 = hidden[b]
        const float* hp = hidden + (size_t)b * Hc + 2 * t;
        s_zpk[t] = pk_rne(hp[0], hp[1]);
    }
    if (t >= 128 && t < 192) {  // stage x for step 0
        int m = t - 128;
        const float* xp = x + ((size_t)b * T + 0) * Ic + 2 * m;
        s_zpk[128 + m] = pk_rne(xp[0], xp[1]);
    }
    __syncthreads();

    float c0 = 0.f, c1 = 0.f;
    for (int s = 0; s < Ts; s++) {
        const int par = s & 1;
        uint32_t vz0 = s_zpk[ks * 48 + (lane < 48 ? lane : 0)];
        float a0 = bias, a1 = 0.f, a2 = 0.f, a3 = 0.f;
#pragma unroll
        for (int k = 0; k < 48; k += 4) {
            a0 = dot2acc(rl(vz0, k + 0), w_pk[k + 0], a0);
            a1 = dot2acc(rl(vz0, k + 1), w_pk[k + 1], a1);
            a2 = dot2acc(rl(vz0, k + 2), w_pk[k + 2], a2);
            a3 = dot2acc(rl(vz0, k + 3), w_pk[k + 3], a3);
        }
        s_part[t] = (a0 + a1) + (a2 + a3);
        __syncthreads();

        if (t < 256) {
            float g = (s_part[t] + s_part[t + 256]) + (s_part[t + 512] + s_part[t + 768]);
            s_g[q4 * 256 + t] = g;
            __hip_atomic_store(&xch_b[par * 1024 + q4 * 256 + t],
                               __builtin_bit_cast(uint32_t, g),
                               __ATOMIC_RELAXED, __HIP_MEMORY_SCOPE_AGENT);
            __threadfence();
        }
        __syncthreads();
        if (t == 0)
            __hip_atomic_store(&flag_b[q4], (uint32_t)(s + 1), __ATOMIC_RELEASE, __HIP_MEMORY_SCOPE_AGENT);
        if (t >= 64 && t < 67) {
            int peer = (q4 + (t - 63)) & 3;
            while (__hip_atomic_load(&flag_b[peer], __ATOMIC_ACQUIRE, __HIP_MEMORY_SCOPE_AGENT) < (uint32_t)(s + 1))
                __builtin_amdgcn_s_sleep(1);
        }
        __syncthreads();
        if (t < 768) {
            int slot = (q4 + 1 + (t >> 8)) & 3;
            int off  = t & 255;
            uint32_t u = __hip_atomic_load(&xch_b[par * 1024 + slot * 256 + off],
                                           __ATOMIC_RELAXED, __HIP_MEMORY_SCOPE_AGENT);
            s_g[slot * 256 + off] = __builtin_bit_cast(float, u);
        }
        __syncthreads();

        if (t < 128) {
            float i0 = s_g[2 * t],       i1 = s_g[2 * t + 1];
            float f0 = s_g[256 + 2 * t], f1 = s_g[256 + 2 * t + 1];
            float g0 = s_g[512 + 2 * t], g1 = s_g[512 + 2 * t + 1];
            float o0 = s_g[768 + 2 * t], o1 = s_g[768 + 2 * t + 1];
            c0 = sigm(f0) * c0 + sigm(i0) * tanh_f(g0);
            c1 = sigm(f1) * c1 + sigm(i1) * tanh_f(g1);
            float h0 = sigm(o0) * tanh_f(c0);
            float h1 = sigm(o1) * tanh_f(c1);
            s_zpk[t] = pk_rne(h0, h1);
        } else if (t < 192) {  // stage x for step s+1
            int sn = s + 1;
            if (sn < Ts) {
                int m = t - 128;
                const float* xp = x + ((size_t)b * T + sn) * Ic + 2 * m;
                s_zpk[128 + m] = pk_rne(xp[0], xp[1]);
            }
        }
        __syncthreads();

        // fused output projection of h_s: this quarter's 32 out rows
        if (t < 512) {
            float p = 0.f;
#pragma unroll
            for (int j = 0; j < 8; j++)
                p = dot2acc(s_zpk[chunk * 8 + j], outw_pk[j], p);
            s_op[t] = p;
        }
        __syncthreads();
        if (t < 32) {
            float y = outb[q4 * 32 + t];
#pragma unroll
            for (int m = 0; m < 16; m++) y += s_op[t * 16 + m];
            out[((size_t)b * Ts + s) * Ic + q4 * 32 + t] = y;
        }
        // next iteration's barriers protect s_part / s_op reuse
    }
}

extern "C" void kernel_launch(void* const* d_in, const int* in_sizes, int n_in,
                              void* d_out, int out_size, void* d_ws, size_t ws_size,
                              hipStream_t stream)
{
    const float* x    = (const float*)d_in[0];
    const float* WihF = (const float*)d_in[1];
    const float* WhhF = (const float*)d_in[2];
    const float* bihF = (const float*)d_in[3];
    const float* bhhF = (const float*)d_in[4];
    const float* WihB = (const float*)d_in[5];
    const float* WhhB = (const float*)d_in[6];
    const float* bihB = (const float*)d_in[7];
    const float* bhhB = (const float*)d_in[8];
    const float* latW = (const float*)d_in[9];
    const float* latb = (const float*)d_in[10];
    const float* l2hW = (const float*)d_in[11];
    const float* l2hb = (const float*)d_in[12];
    const float* dWih = (const float*)d_in[13];
    const float* dWhh = (const float*)d_in[14];
    const float* dbih = (const float*)d_in[15];
    const float* dbhh = (const float*)d_in[16];
    const float* outW = (const float*)d_in[17];
    const float* outb = (const float*)d_in[18];

    const int T = in_sizes[0] / (64 * Ic);  // 4096

    float* ws  = (float*)d_ws;
    float* hFp = ws;                 // [64,256]
    float* hBp = ws + 16384;         // [64,256]
    float* hid = ws + 32768;         // [64,256]
    uint32_t* u = (uint32_t*)(ws + 49152);
    uint32_t* encXch = u;            // 128*2*2*512 = 262144
    uint32_t* decXch = u + 262144;   // 64*2*1024   = 131072
    uint32_t* flg    = u + 393216;   // enc 256 + dec 256
    uint32_t* encFlg = flg;
    uint32_t* decFlg = flg + 256;

    hipMemsetAsync(flg, 0, 512 * sizeof(uint32_t), stream);

    enc_kernel<<<256, NT, 0, stream>>>(x, WihF, WhhF, bihF, bhhF,
                                       WihB, WhhB, bihB, bhhB,
                                       hFp, hBp, encXch, encFlg, T);
    lat_kernel<<<64, 256, 0, stream>>>(hFp, hBp, latW, latb, l2hW, l2hb, hid);
    dec_kernel<<<256, NT, 0, stream>>>(x, dWih, dWhh, dbih, dbhh,
                                       outW, outb, hid, (float*)d_out,
                                       decXch, decFlg, T);
}

// Round 6
// 87795.752 us; speedup vs baseline: 3.3015x; 2.7794x over previous
//
#include <hip/hip_runtime.h>
#include <stdint.h>

#define Ic 128   // input size
#define Hc 256   // hidden size

using half2v = __attribute__((ext_vector_type(2))) _Float16;

__device__ __forceinline__ uint32_t pk_rne(float a, float b) {
    _Float16 lo = (_Float16)a, hi = (_Float16)b;
    return (uint32_t)__builtin_bit_cast(uint16_t, lo) |
           ((uint32_t)__builtin_bit_cast(uint16_t, hi) << 16);
}
__device__ __forceinline__ float dot2acc(uint32_t a, uint32_t b, float c) {
    return __builtin_amdgcn_fdot2(__builtin_bit_cast(half2v, a),
                                  __builtin_bit_cast(half2v, b), c, false);
}
__device__ __forceinline__ uint32_t rl(uint32_t v, int k) {
    return (uint32_t)__builtin_amdgcn_readlane((int)v, k);
}
__device__ __forceinline__ float sigm(float x) {
    return __builtin_amdgcn_rcpf(1.f + __expf(-x));
}
__device__ __forceinline__ float tanh_f(float x) {
    float e = __expf(-2.f * __builtin_fabsf(x));
    float t = (1.f - e) * __builtin_amdgcn_rcpf(1.f + e);
    return __builtin_copysignf(t, x);
}
// payload: relaxed agent store/load; flag: release store / acquire poll.
__device__ __forceinline__ uint32_t aload_rlx(const uint32_t* p) {
    return __hip_atomic_load(p, __ATOMIC_RELAXED, __HIP_MEMORY_SCOPE_AGENT);
}
__device__ __forceinline__ void astore_rlx(uint32_t* p, uint32_t v) {
    __hip_atomic_store(p, v, __ATOMIC_RELAXED, __HIP_MEMORY_SCOPE_AGENT);
}
__device__ __forceinline__ uint32_t aload_acq(const uint32_t* p) {
    return __hip_atomic_load(p, __ATOMIC_ACQUIRE, __HIP_MEMORY_SCOPE_AGENT);
}
__device__ __forceinline__ void astore_rel(uint32_t* p, uint32_t v) {
    __hip_atomic_store(p, v, __ATOMIC_RELEASE, __HIP_MEMORY_SCOPE_AGENT);
}

// ===================== Encoder =====================
// 256 blocks: pair p = (dir,batch); half k owns hidden units [k*128, k*128+128),
// all 4 gates. Thread t: gate = t>>7, unit-local = t&127. Weights register-resident.
// Per-step h-half exchange (64 u32), parity double-buffered.
__global__ __launch_bounds__(512, 2) void enc_kernel(
    const float* __restrict__ x,
    const float* __restrict__ WihF, const float* __restrict__ WhhF,
    const float* __restrict__ bihF, const float* __restrict__ bhhF,
    const float* __restrict__ WihB, const float* __restrict__ WhhB,
    const float* __restrict__ bihB, const float* __restrict__ bhhB,
    float* __restrict__ hF, float* __restrict__ hB,
    uint32_t* __restrict__ xch,    // [128 pairs][2 halves][2 parity][64]
    uint32_t* __restrict__ flags,  // [128 pairs][2]
    int T)
{
    const int t    = threadIdx.x;
    const int lane = t & 63;
    const int g    = blockIdx.x;
    const int half = (g >> 3) & 1;               // pair-mates g and g^8: same XCD
    const int p    = ((g >> 4) << 3) | (g & 7);  // pair id 0..127
    const int rev  = p >> 6;
    const int b    = p & 63;

    const int gate = t >> 7;
    const int ul   = t & 127;
    const int r    = gate * Hc + half * 128 + ul;   // global gate row

    const float* Wih = rev ? WihB : WihF;
    const float* Whh = rev ? WhhB : WhhF;
    const float* bih = rev ? bihB : bihF;
    const float* bhh = rev ? bhhB : bhhF;

    __shared__ uint32_t s_z[192];   // [0:128) h pairs (global unit order), [128:192) x pairs
    __shared__ float    s_g[512];   // local gate rows

    uint32_t whh[128];   // [0:64) own-half h cols, [64:128) peer-half (static indices)
    uint32_t wih[64];
    {
        const float* wr = Whh + (size_t)r * Hc;
        const int ob = half * 64, pb2 = (half ^ 1) * 64;
#pragma unroll
        for (int j = 0; j < 64; j++) whh[j]      = pk_rne(wr[2*(ob+j)],  wr[2*(ob+j)+1]);
#pragma unroll
        for (int j = 0; j < 64; j++) whh[64+j]   = pk_rne(wr[2*(pb2+j)], wr[2*(pb2+j)+1]);
        const float* ir = Wih + (size_t)r * Ic;
#pragma unroll
        for (int j = 0; j < 64; j++) wih[j] = pk_rne(ir[2*j], ir[2*j+1]);
    }
    const float bias = bih[r] + bhh[r];

    const int own_off  = half * 64;
    const int peer_off = (half ^ 1) * 64;
    uint32_t* xch_self  = xch + ((size_t)(p * 2 + half)) * 128;
    uint32_t* xch_peer  = xch + ((size_t)(p * 2 + (half ^ 1))) * 128;
    uint32_t* flag_self = flags + p * 2 + half;
    uint32_t* flag_peer = flags + p * 2 + (half ^ 1);

    if (t < 128) s_z[t] = 0u;     // h0 = 0 (full h locally known)
    if (t >= 128 && t < 192) {    // stage x for step 0
        int m = t - 128;
        int ts0 = rev ? (T - 1) : 0;
        const float* xp = x + ((size_t)b * T + ts0) * Ic + 2 * m;
        s_z[128 + m] = pk_rne(xp[0], xp[1]);
    }
    __syncthreads();

    float c0 = 0.f, c1 = 0.f;   // t<64: cell pairs for own units (2t, 2t+1)
    for (int s = 0; s < T; s++) {
        // ---- phase 1: x-dots + own-h dots (exchange latency hides under this) ----
        uint32_t vzx = s_z[128 + lane];
        uint32_t vzo = s_z[own_off + lane];
        float a0 = bias, a1 = 0.f, a2 = 0.f, a3 = 0.f;
#pragma unroll
        for (int k = 0; k < 64; k += 4) {
            a0 = dot2acc(rl(vzx, k+0), wih[k+0], a0);
            a1 = dot2acc(rl(vzx, k+1), wih[k+1], a1);
            a2 = dot2acc(rl(vzx, k+2), wih[k+2], a2);
            a3 = dot2acc(rl(vzx, k+3), wih[k+3], a3);
        }
#pragma unroll
        for (int k = 0; k < 64; k += 4) {
            a0 = dot2acc(rl(vzo, k+0), whh[k+0], a0);
            a1 = dot2acc(rl(vzo, k+1), whh[k+1], a1);
            a2 = dot2acc(rl(vzo, k+2), whh[k+2], a2);
            a3 = dot2acc(rl(vzo, k+3), whh[k+3], a3);
        }
        // wave 4: acquire-poll peer flag, copy peer h-half into LDS
        if (s > 0 && (t >> 6) == 4) {
            while ((int)aload_acq(flag_peer) < s) __builtin_amdgcn_s_sleep(2);
            asm volatile("" ::: "memory");
            s_z[peer_off + lane] = aload_rlx(&xch_peer[(s & 1) * 64 + lane]);
        }
        __syncthreads();
        // ---- phase 2: peer-h dots ----
        uint32_t vzp = s_z[peer_off + lane];
#pragma unroll
        for (int k = 0; k < 64; k += 4) {
            a0 = dot2acc(rl(vzp, k+0), whh[64+k+0], a0);
            a1 = dot2acc(rl(vzp, k+1), whh[64+k+1], a1);
            a2 = dot2acc(rl(vzp, k+2), whh[64+k+2], a2);
            a3 = dot2acc(rl(vzp, k+3), whh[64+k+3], a3);
        }
        s_g[t] = (a0 + a1) + (a2 + a3);
        __syncthreads();

        const int notlast = (s + 1 < T);
        if (t < 64) {   // own-unit cell update (units 2t, 2t+1 of own half)
            float i0 = s_g[2*t],     i1 = s_g[2*t+1];
            float f0 = s_g[128+2*t], f1 = s_g[128+2*t+1];
            float g0 = s_g[256+2*t], g1 = s_g[256+2*t+1];
            float o0 = s_g[384+2*t], o1 = s_g[384+2*t+1];
            c0 = sigm(f0)*c0 + sigm(i0)*tanh_f(g0);
            c1 = sigm(f1)*c1 + sigm(i1)*tanh_f(g1);
            float h0 = sigm(o0)*tanh_f(c0);
            float h1 = sigm(o1)*tanh_f(c1);
            uint32_t hp = pk_rne(h0, h1);
            s_z[own_off + t] = hp;
            if (notlast) {
                astore_rlx(&xch_self[((s+1) & 1) * 64 + t], hp);
            } else {
                float* ho = (rev ? hB : hF) + (size_t)b * Hc + half * 128 + 2 * t;
                ho[0] = h0; ho[1] = h1;
            }
        } else if (t < 128 && notlast) {   // stage x for step s+1
            int m = t - 64;
            int ts = rev ? (T - 2 - s) : (s + 1);
            const float* xp = x + ((size_t)b * T + ts) * Ic + 2 * m;
            s_z[128 + m] = pk_rne(xp[0], xp[1]);
        }
        __syncthreads();
        // release drains wave-0's payload stores (same wave) before flag lands
        if (t == 0 && notlast)
            astore_rel(flag_self, (uint32_t)(s + 1));
    }
}

// ===================== Latent bottleneck =====================
__global__ void lat_kernel(const float* __restrict__ hF, const float* __restrict__ hB,
                           const float* __restrict__ latW, const float* __restrict__ latb,
                           const float* __restrict__ l2hW, const float* __restrict__ l2hb,
                           float* __restrict__ hidden)
{
    int b = blockIdx.x, t = threadIdx.x;  // 256 threads
    __shared__ float s_hn[512];
    __shared__ float s_lat[64];
    s_hn[t]       = hF[(size_t)b * Hc + t];
    s_hn[256 + t] = hB[(size_t)b * Hc + t];
    __syncthreads();
    if (t < 64) {
        float a = latb[t];
        const float* wp = latW + (size_t)t * 512;
        for (int k = 0; k < 512; k++) a += wp[k] * s_hn[k];
        s_lat[t] = a;
    }
    __syncthreads();
    float a = l2hb[t];
    const float* wp = l2hW + (size_t)t * 64;
#pragma unroll
    for (int k = 0; k < 64; k++) a += wp[k] * s_lat[k];
    hidden[(size_t)b * Hc + t] = a;
}

// ===================== Decoder =====================
// 128 blocks = 64 batches × 2 halves. Hidden-split recurrence as encoder.
// Fused output projection (half 0 only): wave-uniform chunk mapping —
// wave w, lane l: ksl = w>>1 (chunk of 64 h-cols, UNIFORM per wave), orow = (w&1)*64+l.
// readlane sources vlo/vhi are lane-indexed h arrays; selection by ksl is uniform.
__global__ __launch_bounds__(512, 2) void dec_kernel(
    const float* __restrict__ x,
    const float* __restrict__ Wih, const float* __restrict__ Whh,
    const float* __restrict__ bih, const float* __restrict__ bhh,
    const float* __restrict__ outW, const float* __restrict__ outb,
    const float* __restrict__ hidden, float* __restrict__ out,
    uint32_t* __restrict__ xch,    // [64 batches][2 halves][2 parity][64]
    uint32_t* __restrict__ flags,  // [64][2]
    int T)
{
    const int t    = threadIdx.x;
    const int lane = t & 63;
    const int g    = blockIdx.x;
    const int half = (g >> 3) & 1;
    const int b    = ((g >> 4) << 3) | (g & 7);   // 0..63
    const int Ts   = T - 1;

    const int gate = t >> 7;
    const int ul   = t & 127;
    const int r    = gate * Hc + half * 128 + ul;

    __shared__ uint32_t s_z[192];
    __shared__ float    s_g[512];
    __shared__ float    s_op[512];
    __shared__ uint32_t s_ow[32 * 512];   // outW packed, keyed by thread: [j][t]

    uint32_t whh[128], wih[64];
    {
        const float* wr = Whh + (size_t)r * Hc;
        const int ob = half * 64, pb2 = (half ^ 1) * 64;
#pragma unroll
        for (int j = 0; j < 64; j++) whh[j]    = pk_rne(wr[2*(ob+j)],  wr[2*(ob+j)+1]);
#pragma unroll
        for (int j = 0; j < 64; j++) whh[64+j] = pk_rne(wr[2*(pb2+j)], wr[2*(pb2+j)+1]);
        const float* ir = Wih + (size_t)r * Ic;
#pragma unroll
        for (int j = 0; j < 64; j++) wih[j] = pk_rne(ir[2*j], ir[2*j+1]);
    }
    const float bias = bih[r] + bhh[r];

    // projection mapping: wave-uniform chunk
    const int ksl  = t >> 7;              // == wave>>1, uniform per wave (0..3)
    const int orow = ((t >> 6) & 1) * 64 + lane;   // out row 0..127
    if (half == 0) {   // stage outW into LDS, keyed by t
        const float* op = outW + (size_t)orow * Hc + (size_t)ksl * 64;
#pragma unroll
        for (int j = 0; j < 32; j++)
            s_ow[j * 512 + t] = pk_rne(op[2*j], op[2*j+1]);
    }
    const float outb_r = (t >= 128 && t < 256) ? outb[t - 128] : 0.f;

    const int own_off  = half * 64;
    const int peer_off = (half ^ 1) * 64;
    uint32_t* xch_self  = xch + ((size_t)(b * 2 + half)) * 128;
    uint32_t* xch_peer  = xch + ((size_t)(b * 2 + (half ^ 1))) * 128;
    uint32_t* flag_self = flags + b * 2 + half;
    uint32_t* flag_peer = flags + b * 2 + (half ^ 1);

    if (t < 128) {   // h0 = hidden[b] (full h locally known)
        const float* hp = hidden + (size_t)b * Hc + 2 * t;
        s_z[t] = pk_rne(hp[0], hp[1]);
    }
    if (t >= 128 && t < 192) {   // stage x for step 0
        int m = t - 128;
        const float* xp = x + ((size_t)b * T) * Ic + 2 * m;
        s_z[128 + m] = pk_rne(xp[0], xp[1]);
    }
    __syncthreads();

    float c0 = 0.f, c1 = 0.f;
    for (int s = 0; s < Ts; s++) {
        uint32_t vzx = s_z[128 + lane];
        uint32_t vzo = s_z[own_off + lane];
        float a0 = bias, a1 = 0.f, a2 = 0.f, a3 = 0.f;
#pragma unroll
        for (int k = 0; k < 64; k += 4) {
            a0 = dot2acc(rl(vzx, k+0), wih[k+0], a0);
            a1 = dot2acc(rl(vzx, k+1), wih[k+1], a1);
            a2 = dot2acc(rl(vzx, k+2), wih[k+2], a2);
            a3 = dot2acc(rl(vzx, k+3), wih[k+3], a3);
        }
#pragma unroll
        for (int k = 0; k < 64; k += 4) {
            a0 = dot2acc(rl(vzo, k+0), whh[k+0], a0);
            a1 = dot2acc(rl(vzo, k+1), whh[k+1], a1);
            a2 = dot2acc(rl(vzo, k+2), whh[k+2], a2);
            a3 = dot2acc(rl(vzo, k+3), whh[k+3], a3);
        }
        if (s > 0 && (t >> 6) == 4) {
            while ((int)aload_acq(flag_peer) < s) __builtin_amdgcn_s_sleep(2);
            asm volatile("" ::: "memory");
            s_z[peer_off + lane] = aload_rlx(&xch_peer[(s & 1) * 64 + lane]);
        }
        __syncthreads();
        uint32_t vzp = s_z[peer_off + lane];
#pragma unroll
        for (int k = 0; k < 64; k += 4) {
            a0 = dot2acc(rl(vzp, k+0), whh[64+k+0], a0);
            a1 = dot2acc(rl(vzp, k+1), whh[64+k+1], a1);
            a2 = dot2acc(rl(vzp, k+2), whh[64+k+2], a2);
            a3 = dot2acc(rl(vzp, k+3), whh[64+k+3], a3);
        }
        s_g[t] = (a0 + a1) + (a2 + a3);

        if (half == 0 && s > 0) {   // projection of h_s -> decoded[s-1] partials
            // half==0: vzo = h units [0,128) pairs, vzp = units [128,256) pairs
            const int kb = (ksl & 1) * 32;
            float p0 = 0.f, p1 = 0.f;
#pragma unroll
            for (int j = 0; j < 32; j += 2) {
                uint32_t h0b = (ksl < 2) ? rl(vzo, kb + j)     : rl(vzp, kb + j);
                uint32_t h1b = (ksl < 2) ? rl(vzo, kb + j + 1) : rl(vzp, kb + j + 1);
                p0 = dot2acc(h0b, s_ow[(j)     * 512 + t], p0);
                p1 = dot2acc(h1b, s_ow[(j + 1) * 512 + t], p1);
            }
            s_op[orow * 4 + ksl] = p0 + p1;
        }
        __syncthreads();

        if (t < 64) {
            float i0 = s_g[2*t],     i1 = s_g[2*t+1];
            float f0 = s_g[128+2*t], f1 = s_g[128+2*t+1];
            float g0 = s_g[256+2*t], g1 = s_g[256+2*t+1];
            float o0 = s_g[384+2*t], o1 = s_g[384+2*t+1];
            c0 = sigm(f0)*c0 + sigm(i0)*tanh_f(g0);
            c1 = sigm(f1)*c1 + sigm(i1)*tanh_f(g1);
            float h0 = sigm(o0)*tanh_f(c0);
            float h1 = sigm(o1)*tanh_f(c1);
            uint32_t hp = pk_rne(h0, h1);
            s_z[own_off + t] = hp;
            astore_rlx(&xch_self[((s+1) & 1) * 64 + t], hp);   // peer tail needs h_Ts too
        } else if (t < 128) {
            if (s + 1 < Ts) {
                int m = t - 64;
                const float* xp = x + ((size_t)b * T + (s + 1)) * Ic + 2 * m;
                s_z[128 + m] = pk_rne(xp[0], xp[1]);
            }
        } else if (t < 256 && s > 0 && half == 0) {   // reduce + store decoded[b, s-1]
            int rr = t - 128;
            float y = outb_r + ((s_op[rr*4+0] + s_op[rr*4+1]) + (s_op[rr*4+2] + s_op[rr*4+3]));
            out[((size_t)b * Ts + (s - 1)) * Ic + rr] = y;
        }
        __syncthreads();
        if (t == 0)
            astore_rel(flag_self, (uint32_t)(s + 1));
    }

    // tail: decoded[b, Ts-1] from h_Ts (half 0 only computes/stores)
    if ((t >> 6) == 4) {
        while ((int)aload_acq(flag_peer) < Ts) __builtin_amdgcn_s_sleep(2);
        asm volatile("" ::: "memory");
        s_z[peer_off + lane] = aload_rlx(&xch_peer[(Ts & 1) * 64 + lane]);
    }
    __syncthreads();
    if (half == 0) {
        uint32_t vzo2 = s_z[own_off + lane];    // units [0,128) pairs
        uint32_t vzp2 = s_z[peer_off + lane];   // units [128,256) pairs
        const int kb = (ksl & 1) * 32;
        float p0 = 0.f, p1 = 0.f;
#pragma unroll
        for (int j = 0; j < 32; j += 2) {
            uint32_t h0b = (ksl < 2) ? rl(vzo2, kb + j)     : rl(vzp2, kb + j);
            uint32_t h1b = (ksl < 2) ? rl(vzo2, kb + j + 1) : rl(vzp2, kb + j + 1);
            p0 = dot2acc(h0b, s_ow[(j)     * 512 + t], p0);
            p1 = dot2acc(h1b, s_ow[(j + 1) * 512 + t], p1);
        }
        s_op[orow * 4 + ksl] = p0 + p1;
    }
    __syncthreads();
    if (t >= 128 && t < 256 && half == 0) {
        int rr = t - 128;
        float y = outb_r + ((s_op[rr*4+0] + s_op[rr*4+1]) + (s_op[rr*4+2] + s_op[rr*4+3]));
        out[((size_t)b * Ts + (Ts - 1)) * Ic + rr] = y;
    }
}

extern "C" void kernel_launch(void* const* d_in, const int* in_sizes, int n_in,
                              void* d_out, int out_size, void* d_ws, size_t ws_size,
                              hipStream_t stream)
{
    const float* x    = (const float*)d_in[0];
    const float* WihF = (const float*)d_in[1];
    const float* WhhF = (const float*)d_in[2];
    const float* bihF = (const float*)d_in[3];
    const float* bhhF = (const float*)d_in[4];
    const float* WihB = (const float*)d_in[5];
    const float* WhhB = (const float*)d_in[6];
    const float* bihB = (const float*)d_in[7];
    const float* bhhB = (const float*)d_in[8];
    const float* latW = (const float*)d_in[9];
    const float* latb = (const float*)d_in[10];
    const float* l2hW = (const float*)d_in[11];
    const float* l2hb = (const float*)d_in[12];
    const float* dWih = (const float*)d_in[13];
    const float* dWhh = (const float*)d_in[14];
    const float* dbih = (const float*)d_in[15];
    const float* dbhh = (const float*)d_in[16];
    const float* outW = (const float*)d_in[17];
    const float* outb = (const float*)d_in[18];

    const int T = in_sizes[0] / (64 * Ic);  // 4096

    float* ws  = (float*)d_ws;
    float* hFp = ws;                 // [64,256]
    float* hBp = ws + 16384;         // [64,256]
    float* hid = ws + 32768;         // [64,256]
    uint32_t* u = (uint32_t*)(ws + 49152);
    uint32_t* encXch = u;            // 128*2*2*64 = 32768
    uint32_t* decXch = u + 32768;    // 64*2*2*64  = 16384
    uint32_t* flg    = u + 49152;    // enc 256 + dec 128
    uint32_t* encFlg = flg;
    uint32_t* decFlg = flg + 256;

    hipMemsetAsync(flg, 0, 512 * sizeof(uint32_t), stream);

    enc_kernel<<<256, 512, 0, stream>>>(x, WihF, WhhF, bihF, bhhF,
                                        WihB, WhhB, bihB, bhhB,
                                        hFp, hBp, encXch, encFlg, T);
    lat_kernel<<<64, 256, 0, stream>>>(hFp, hBp, latW, latb, l2hW, l2hb, hid);
    dec_kernel<<<128, 512, 0, stream>>>(x, dWih, dWhh, dbih, dbhh,
                                        outW, outb, hid, (float*)d_out,
                                        decXch, decFlg, T);
}

// Round 7
// 43324.112 us; speedup vs baseline: 6.6905x; 2.0265x over previous
//
#include <hip/hip_runtime.h>
#include <stdint.h>

#define Ic 128   // input size
#define Hc 256   // hidden size

typedef unsigned long long u64;
using half2v = __attribute__((ext_vector_type(2))) _Float16;

__device__ __forceinline__ uint32_t pk_rne(float a, float b) {
    _Float16 lo = (_Float16)a, hi = (_Float16)b;
    return (uint32_t)__builtin_bit_cast(uint16_t, lo) |
           ((uint32_t)__builtin_bit_cast(uint16_t, hi) << 16);
}
__device__ __forceinline__ float dot2acc(uint32_t a, uint32_t b, float c) {
    return __builtin_amdgcn_fdot2(__builtin_bit_cast(half2v, a),
                                  __builtin_bit_cast(half2v, b), c, false);
}
__device__ __forceinline__ uint32_t rl(uint32_t v, int k) {
    return (uint32_t)__builtin_amdgcn_readlane((int)v, k);
}
__device__ __forceinline__ float sigm(float x) {
    return __builtin_amdgcn_rcpf(1.f + __expf(-x));
}
__device__ __forceinline__ float tanh_f(float x) {
    float e = __expf(-2.f * __builtin_fabsf(x));
    float t = (1.f - e) * __builtin_amdgcn_rcpf(1.f + e);
    return __builtin_copysignf(t, x);
}
// Tagged-slot exchange: (tag<<32)|payload in ONE u64, relaxed agent atomics only.
// Per-location coherence orders tag with data — no acquire/release, no fences,
// no L2 maintenance. Tags strictly increase; parity double-buffer prevents
// producer overrun (writer of tag s+3 needs peer tag s+2 which needed our s+1).
__device__ __forceinline__ u64 aload64(const u64* p) {
    return __hip_atomic_load(p, __ATOMIC_RELAXED, __HIP_MEMORY_SCOPE_AGENT);
}
__device__ __forceinline__ void astore64(u64* p, u64 v) {
    __hip_atomic_store(p, v, __ATOMIC_RELAXED, __HIP_MEMORY_SCOPE_AGENT);
}

// ===================== Encoder =====================
// 256 blocks: pair p = (dir,batch); half k owns hidden units [k*128, k*128+128),
// all 4 gates. Thread t: gate = t>>7, unit-local = t&127. Weights register/AGPR-resident.
// Per-step h-half exchange: 64 tagged u64 slots, parity double-buffered.
__global__ __launch_bounds__(512, 2) void enc_kernel(
    const float* __restrict__ x,
    const float* __restrict__ WihF, const float* __restrict__ WhhF,
    const float* __restrict__ bihF, const float* __restrict__ bhhF,
    const float* __restrict__ WihB, const float* __restrict__ WhhB,
    const float* __restrict__ bihB, const float* __restrict__ bhhB,
    float* __restrict__ hF, float* __restrict__ hB,
    u64* __restrict__ xch,    // [128 pairs][2 halves][2 parity][64]
    int T)
{
    const int t    = threadIdx.x;
    const int lane = t & 63;
    const int g    = blockIdx.x;
    const int half = (g >> 3) & 1;               // pair-mates g and g^8: same XCD
    const int p    = ((g >> 4) << 3) | (g & 7);  // pair id 0..127
    const int rev  = p >> 6;
    const int b    = p & 63;

    const int gate = t >> 7;
    const int ul   = t & 127;
    const int r    = gate * Hc + half * 128 + ul;   // global gate row

    const float* Wih = rev ? WihB : WihF;
    const float* Whh = rev ? WhhB : WhhF;
    const float* bih = rev ? bihB : bihF;
    const float* bhh = rev ? bhhB : bhhF;

    __shared__ uint32_t s_z[192];   // [0:128) h pairs (global unit order), [128:192) x pairs
    __shared__ float    s_g[512];   // local gate rows

    uint32_t whh[128];   // [0:64) own-half h cols, [64:128) peer-half (static indices)
    uint32_t wih[64];
    {
        const float* wr = Whh + (size_t)r * Hc;
        const int ob = half * 64, pb2 = (half ^ 1) * 64;
#pragma unroll
        for (int j = 0; j < 64; j++) whh[j]      = pk_rne(wr[2*(ob+j)],  wr[2*(ob+j)+1]);
#pragma unroll
        for (int j = 0; j < 64; j++) whh[64+j]   = pk_rne(wr[2*(pb2+j)], wr[2*(pb2+j)+1]);
        const float* ir = Wih + (size_t)r * Ic;
#pragma unroll
        for (int j = 0; j < 64; j++) wih[j] = pk_rne(ir[2*j], ir[2*j+1]);
    }
    const float bias = bih[r] + bhh[r];

    const int own_off  = half * 64;
    const int peer_off = (half ^ 1) * 64;
    u64* xch_self = xch + ((size_t)(p * 2 + half)) * 128;        // 2 parity × 64
    u64* xch_peer = xch + ((size_t)(p * 2 + (half ^ 1))) * 128;

    if (t < 128) s_z[t] = 0u;     // h0 = 0 (full h locally known)
    if (t >= 128 && t < 192) {    // stage x for step 0
        int m = t - 128;
        int ts0 = rev ? (T - 1) : 0;
        const float* xp = x + ((size_t)b * T + ts0) * Ic + 2 * m;
        s_z[128 + m] = pk_rne(xp[0], xp[1]);
    }
    __syncthreads();

    float c0 = 0.f, c1 = 0.f;   // t<64: cell pairs for own units (2t, 2t+1)
    for (int s = 0; s < T; s++) {
        // ---- phase 1: x-dots + own-h dots (exchange latency hides under this) ----
        uint32_t vzx = s_z[128 + lane];
        uint32_t vzo = s_z[own_off + lane];
        float a0 = bias, a1 = 0.f, a2 = 0.f, a3 = 0.f;
#pragma unroll
        for (int k = 0; k < 64; k += 4) {
            a0 = dot2acc(rl(vzx, k+0), wih[k+0], a0);
            a1 = dot2acc(rl(vzx, k+1), wih[k+1], a1);
            a2 = dot2acc(rl(vzx, k+2), wih[k+2], a2);
            a3 = dot2acc(rl(vzx, k+3), wih[k+3], a3);
        }
#pragma unroll
        for (int k = 0; k < 64; k += 4) {
            a0 = dot2acc(rl(vzo, k+0), whh[k+0], a0);
            a1 = dot2acc(rl(vzo, k+1), whh[k+1], a1);
            a2 = dot2acc(rl(vzo, k+2), whh[k+2], a2);
            a3 = dot2acc(rl(vzo, k+3), whh[k+3], a3);
        }
        // wave 4: poll tagged peer slots (per-lane), copy peer h-half into LDS
        if (s > 0 && (t >> 6) == 4) {
            u64 v;
            while ((int)((v = aload64(&xch_peer[(s & 1) * 64 + lane])) >> 32) < s)
                __builtin_amdgcn_s_sleep(1);
            s_z[peer_off + lane] = (uint32_t)v;   // data-dependent on tag: no fence needed
        }
        __syncthreads();
        // ---- phase 2: peer-h dots ----
        uint32_t vzp = s_z[peer_off + lane];
#pragma unroll
        for (int k = 0; k < 64; k += 4) {
            a0 = dot2acc(rl(vzp, k+0), whh[64+k+0], a0);
            a1 = dot2acc(rl(vzp, k+1), whh[64+k+1], a1);
            a2 = dot2acc(rl(vzp, k+2), whh[64+k+2], a2);
            a3 = dot2acc(rl(vzp, k+3), whh[64+k+3], a3);
        }
        s_g[t] = (a0 + a1) + (a2 + a3);
        __syncthreads();

        const int notlast = (s + 1 < T);
        if (t < 64) {   // own-unit cell update (units 2t, 2t+1 of own half)
            float i0 = s_g[2*t],     i1 = s_g[2*t+1];
            float f0 = s_g[128+2*t], f1 = s_g[128+2*t+1];
            float g0 = s_g[256+2*t], g1 = s_g[256+2*t+1];
            float o0 = s_g[384+2*t], o1 = s_g[384+2*t+1];
            c0 = sigm(f0)*c0 + sigm(i0)*tanh_f(g0);
            c1 = sigm(f1)*c1 + sigm(i1)*tanh_f(g1);
            float h0 = sigm(o0)*tanh_f(c0);
            float h1 = sigm(o1)*tanh_f(c1);
            uint32_t hp = pk_rne(h0, h1);
            s_z[own_off + t] = hp;
            if (notlast) {
                astore64(&xch_self[((s+1) & 1) * 64 + t],
                         ((u64)(uint32_t)(s + 1) << 32) | (u64)hp);
            } else {
                float* ho = (rev ? hB : hF) + (size_t)b * Hc + half * 128 + 2 * t;
                ho[0] = h0; ho[1] = h1;
            }
        } else if (t < 128 && notlast) {   // stage x for step s+1
            int m = t - 64;
            int ts = rev ? (T - 2 - s) : (s + 1);
            const float* xp = x + ((size_t)b * T + ts) * Ic + 2 * m;
            s_z[128 + m] = pk_rne(xp[0], xp[1]);
        }
        __syncthreads();
    }
}

// ===================== Latent bottleneck =====================
__global__ void lat_kernel(const float* __restrict__ hF, const float* __restrict__ hB,
                           const float* __restrict__ latW, const float* __restrict__ latb,
                           const float* __restrict__ l2hW, const float* __restrict__ l2hb,
                           float* __restrict__ hidden)
{
    int b = blockIdx.x, t = threadIdx.x;  // 256 threads
    __shared__ float s_hn[512];
    __shared__ float s_lat[64];
    s_hn[t]       = hF[(size_t)b * Hc + t];
    s_hn[256 + t] = hB[(size_t)b * Hc + t];
    __syncthreads();
    if (t < 64) {
        float a = latb[t];
        const float* wp = latW + (size_t)t * 512;
        for (int k = 0; k < 512; k++) a += wp[k] * s_hn[k];
        s_lat[t] = a;
    }
    __syncthreads();
    float a = l2hb[t];
    const float* wp = l2hW + (size_t)t * 64;
#pragma unroll
    for (int k = 0; k < 64; k++) a += wp[k] * s_lat[k];
    hidden[(size_t)b * Hc + t] = a;
}

// ===================== Decoder =====================
// 128 blocks = 64 batches × 2 halves. Hidden-split recurrence as encoder.
// Output projection BALANCED: each half computes/stores its own 64 out rows.
// t<256: wave w = ksl = t>>6 (uniform), local row = lane; weights in LDS
// s_ow[j*256+t]. Projection runs in phase 2 (h_s complete in s_z).
__global__ __launch_bounds__(512, 2) void dec_kernel(
    const float* __restrict__ x,
    const float* __restrict__ Wih, const float* __restrict__ Whh,
    const float* __restrict__ bih, const float* __restrict__ bhh,
    const float* __restrict__ outW, const float* __restrict__ outb,
    const float* __restrict__ hidden, float* __restrict__ out,
    u64* __restrict__ xch,    // [64 batches][2 halves][2 parity][64]
    int T)
{
    const int t    = threadIdx.x;
    const int lane = t & 63;
    const int g    = blockIdx.x;
    const int half = (g >> 3) & 1;
    const int b    = ((g >> 4) << 3) | (g & 7);   // 0..63
    const int Ts   = T - 1;

    const int gate = t >> 7;
    const int ul   = t & 127;
    const int r    = gate * Hc + half * 128 + ul;

    __shared__ uint32_t s_z[192];
    __shared__ float    s_g[512];
    __shared__ float    s_op[256];
    __shared__ uint32_t s_ow[32 * 256];   // own 64 outW rows packed, keyed by t<256

    uint32_t whh[128], wih[64];
    {
        const float* wr = Whh + (size_t)r * Hc;
        const int ob = half * 64, pb2 = (half ^ 1) * 64;
#pragma unroll
        for (int j = 0; j < 64; j++) whh[j]    = pk_rne(wr[2*(ob+j)],  wr[2*(ob+j)+1]);
#pragma unroll
        for (int j = 0; j < 64; j++) whh[64+j] = pk_rne(wr[2*(pb2+j)], wr[2*(pb2+j)+1]);
        const float* ir = Wih + (size_t)r * Ic;
#pragma unroll
        for (int j = 0; j < 64; j++) wih[j] = pk_rne(ir[2*j], ir[2*j+1]);
    }
    const float bias = bih[r] + bhh[r];

    // projection mapping (t<256): ksl = t>>6 (wave-uniform 0..3), out row = half*64+lane
    const int ksl = t >> 6;
    if (t < 256) {   // stage own half's outW rows into LDS
        const float* op = outW + (size_t)(half * 64 + lane) * Hc + (size_t)ksl * 64;
#pragma unroll
        for (int j = 0; j < 32; j++)
            s_ow[j * 256 + t] = pk_rne(op[2*j], op[2*j+1]);
    }
    const float outb_r = (t >= 256 && t < 320) ? outb[half * 64 + (t - 256)] : 0.f;

    const int own_off  = half * 64;
    const int peer_off = (half ^ 1) * 64;
    u64* xch_self = xch + ((size_t)(b * 2 + half)) * 128;
    u64* xch_peer = xch + ((size_t)(b * 2 + (half ^ 1))) * 128;

    if (t < 128) {   // h0 = hidden[b] (full h locally known)
        const float* hp = hidden + (size_t)b * Hc + 2 * t;
        s_z[t] = pk_rne(hp[0], hp[1]);
    }
    if (t >= 128 && t < 192) {   // stage x for step 0
        int m = t - 128;
        const float* xp = x + ((size_t)b * T) * Ic + 2 * m;
        s_z[128 + m] = pk_rne(xp[0], xp[1]);
    }
    __syncthreads();

    float c0 = 0.f, c1 = 0.f;
    for (int s = 0; s < Ts; s++) {
        uint32_t vzx = s_z[128 + lane];
        uint32_t vzo = s_z[own_off + lane];
        float a0 = bias, a1 = 0.f, a2 = 0.f, a3 = 0.f;
#pragma unroll
        for (int k = 0; k < 64; k += 4) {
            a0 = dot2acc(rl(vzx, k+0), wih[k+0], a0);
            a1 = dot2acc(rl(vzx, k+1), wih[k+1], a1);
            a2 = dot2acc(rl(vzx, k+2), wih[k+2], a2);
            a3 = dot2acc(rl(vzx, k+3), wih[k+3], a3);
        }
#pragma unroll
        for (int k = 0; k < 64; k += 4) {
            a0 = dot2acc(rl(vzo, k+0), whh[k+0], a0);
            a1 = dot2acc(rl(vzo, k+1), whh[k+1], a1);
            a2 = dot2acc(rl(vzo, k+2), whh[k+2], a2);
            a3 = dot2acc(rl(vzo, k+3), whh[k+3], a3);
        }
        if (s > 0 && (t >> 6) == 4) {
            u64 v;
            while ((int)((v = aload64(&xch_peer[(s & 1) * 64 + lane])) >> 32) < s)
                __builtin_amdgcn_s_sleep(1);
            s_z[peer_off + lane] = (uint32_t)v;
        }
        __syncthreads();
        uint32_t vzp = s_z[peer_off + lane];
#pragma unroll
        for (int k = 0; k < 64; k += 4) {
            a0 = dot2acc(rl(vzp, k+0), whh[64+k+0], a0);
            a1 = dot2acc(rl(vzp, k+1), whh[64+k+1], a1);
            a2 = dot2acc(rl(vzp, k+2), whh[64+k+2], a2);
            a3 = dot2acc(rl(vzp, k+3), whh[64+k+3], a3);
        }
        s_g[t] = (a0 + a1) + (a2 + a3);

        if (s > 0 && t < 256) {   // projection of h_s -> decoded[s-1] partials
            uint32_t vplo = s_z[lane];        // h pairs 0..63   (units 0..127)
            uint32_t vphi = s_z[64 + lane];   // h pairs 64..127 (units 128..255)
            const int kb = (ksl & 1) * 32;
            float p0 = 0.f, p1 = 0.f;
#pragma unroll
            for (int j = 0; j < 32; j += 2) {
                uint32_t h0b = (ksl < 2) ? rl(vplo, kb + j)     : rl(vphi, kb + j);
                uint32_t h1b = (ksl < 2) ? rl(vplo, kb + j + 1) : rl(vphi, kb + j + 1);
                p0 = dot2acc(h0b, s_ow[(j)     * 256 + t], p0);
                p1 = dot2acc(h1b, s_ow[(j + 1) * 256 + t], p1);
            }
            s_op[lane * 4 + ksl] = p0 + p1;
        }
        __syncthreads();

        if (t < 64) {
            float i0 = s_g[2*t],     i1 = s_g[2*t+1];
            float f0 = s_g[128+2*t], f1 = s_g[128+2*t+1];
            float g0 = s_g[256+2*t], g1 = s_g[256+2*t+1];
            float o0 = s_g[384+2*t], o1 = s_g[384+2*t+1];
            c0 = sigm(f0)*c0 + sigm(i0)*tanh_f(g0);
            c1 = sigm(f1)*c1 + sigm(i1)*tanh_f(g1);
            float h0 = sigm(o0)*tanh_f(c0);
            float h1 = sigm(o1)*tanh_f(c1);
            uint32_t hp = pk_rne(h0, h1);
            s_z[own_off + t] = hp;
            astore64(&xch_self[((s+1) & 1) * 64 + t],
                     ((u64)(uint32_t)(s + 1) << 32) | (u64)hp);   // tail needs h_Ts
        } else if (t < 128) {
            if (s + 1 < Ts) {
                int m = t - 64;
                const float* xp = x + ((size_t)b * T + (s + 1)) * Ic + 2 * m;
                s_z[128 + m] = pk_rne(xp[0], xp[1]);
            }
        } else if (t >= 256 && t < 320 && s > 0) {   // reduce + store own out rows
            int rr = t - 256;
            float y = outb_r + ((s_op[rr*4+0] + s_op[rr*4+1]) + (s_op[rr*4+2] + s_op[rr*4+3]));
            out[((size_t)b * Ts + (s - 1)) * Ic + half * 64 + rr] = y;
        }
        __syncthreads();
    }

    // tail: decoded[b, Ts-1] from h_Ts
    if ((t >> 6) == 4) {
        u64 v;
        while ((int)((v = aload64(&xch_peer[(Ts & 1) * 64 + lane])) >> 32) < Ts)
            __builtin_amdgcn_s_sleep(1);
        s_z[peer_off + lane] = (uint32_t)v;
    }
    __syncthreads();
    if (t < 256) {
        uint32_t vplo = s_z[lane];
        uint32_t vphi = s_z[64 + lane];
        const int kb = (ksl & 1) * 32;
        float p0 = 0.f, p1 = 0.f;
#pragma unroll
        for (int j = 0; j < 32; j += 2) {
            uint32_t h0b = (ksl < 2) ? rl(vplo, kb + j)     : rl(vphi, kb + j);
            uint32_t h1b = (ksl < 2) ? rl(vplo, kb + j + 1) : rl(vphi, kb + j + 1);
            p0 = dot2acc(h0b, s_ow[(j)     * 256 + t], p0);
            p1 = dot2acc(h1b, s_ow[(j + 1) * 256 + t], p1);
        }
        s_op[lane * 4 + ksl] = p0 + p1;
    }
    __syncthreads();
    if (t >= 256 && t < 320) {
        int rr = t - 256;
        float y = outb_r + ((s_op[rr*4+0] + s_op[rr*4+1]) + (s_op[rr*4+2] + s_op[rr*4+3]));
        out[((size_t)b * Ts + (Ts - 1)) * Ic + half * 64 + rr] = y;
    }
}

extern "C" void kernel_launch(void* const* d_in, const int* in_sizes, int n_in,
                              void* d_out, int out_size, void* d_ws, size_t ws_size,
                              hipStream_t stream)
{
    const float* x    = (const float*)d_in[0];
    const float* WihF = (const float*)d_in[1];
    const float* WhhF = (const float*)d_in[2];
    const float* bihF = (const float*)d_in[3];
    const float* bhhF = (const float*)d_in[4];
    const float* WihB = (const float*)d_in[5];
    const float* WhhB = (const float*)d_in[6];
    const float* bihB = (const float*)d_in[7];
    const float* bhhB = (const float*)d_in[8];
    const float* latW = (const float*)d_in[9];
    const float* latb = (const float*)d_in[10];
    const float* l2hW = (const float*)d_in[11];
    const float* l2hb = (const float*)d_in[12];
    const float* dWih = (const float*)d_in[13];
    const float* dWhh = (const float*)d_in[14];
    const float* dbih = (const float*)d_in[15];
    const float* dbhh = (const float*)d_in[16];
    const float* outW = (const float*)d_in[17];
    const float* outb = (const float*)d_in[18];

    const int T = in_sizes[0] / (64 * Ic);  // 4096

    float* ws  = (float*)d_ws;
    float* hFp = ws;                 // [64,256]
    float* hBp = ws + 16384;         // [64,256]
    float* hid = ws + 32768;         // [64,256]
    u64* encXch = (u64*)(ws + 49152);   // 128*2*2*64 = 32768 u64
    u64* decXch = encXch + 32768;       // 64*2*2*64  = 16384 u64

    // zero all tags (graph replay must restart deterministically)
    hipMemsetAsync(encXch, 0, (32768 + 16384) * sizeof(u64), stream);

    enc_kernel<<<256, 512, 0, stream>>>(x, WihF, WhhF, bihF, bhhF,
                                        WihB, WhhB, bihB, bhhB,
                                        hFp, hBp, encXch, T);
    lat_kernel<<<64, 256, 0, stream>>>(hFp, hBp, latW, latb, l2hW, l2hb, hid);
    dec_kernel<<<128, 512, 0, stream>>>(x, dWih, dWhh, dbih, dbhh,
                                        outW, outb, hid, (float*)d_out,
                                        decXch, T);
}